// Round 9
// baseline (303.902 us; speedup 1.0000x reference)
//
#include <hip/hip_runtime.h>
#include <hip/hip_fp16.h>
#include <math.h>

#define NUM_PAIRS 10
#define BK_SHIFT 10                // 1024 nodes per bucket
#define BK_NODES 1024
#define MAX_BK 128
#define EPB 8192                   // edges per bin block (75.4KB LDS, 2 blk/CU)
#define BIN_T 512                  // bin block threads (8 waves)
#define NCHUNK 4                   // 4 chunks of 4 edges/thread (16 edges/thread)
#define BCHUNK (BIN_T * 4)         // edges per chunk

__device__ __forceinline__ void load_params(
    int t,
    const float* __restrict__ raw_charges,
    const float* __restrict__ A,
    const float* __restrict__ rho,
    const float* __restrict__ C,
    float* s_AoR, float* s_invRho, float* s_C6, float* s_qq)
{
    if (t < NUM_PAIRS) {
        float r = rho[t];
        float ir = 1.0f / r;
        s_invRho[t] = ir;
        s_AoR[t]    = A[t] * ir;
        s_C6[t]     = 6.0f * C[t];
    }
    if (t < 16) {
        float q0 = raw_charges[0];
        // charges: [Cd, Se, S, Zn] = [q0, -q0, raw[1], raw[2]]
        float qs0 = q0, qs1 = -q0, qs2 = raw_charges[1], qs3 = raw_charges[2];
        float qa = (t & 3) == 0 ? qs0 : (t & 3) == 1 ? qs1 : (t & 3) == 2 ? qs2 : qs3;
        int hb = t >> 2;
        float qb = hb == 0 ? qs0 : hb == 1 ? qs1 : hb == 2 ? qs2 : qs3;
        s_qq[t] = qa * qb;
    }
}

__device__ __forceinline__ float edge_force(
    float d, float inv_d2, int p, int se, int te,
    const float* s_AoR, const float* s_invRho, const float* s_C6, const float* s_qq)
{
    float inv_d  = inv_d2 * d;                 // 1/d without a division
    float inv_d6 = inv_d2 * inv_d2 * inv_d2;
    float pot  = s_AoR[p] * __expf(-d * s_invRho[p]) - s_C6[p] * inv_d6 * inv_d;
    float coul = s_qq[(te << 2) | se] * inv_d2;
    return pot + coul;
}

// 8-byte record: fp16 fx,fy,fz + 10-bit bucket-local node index
__device__ __forceinline__ uint2 pack_rec(float fx, float fy, float fz, int local) {
    unsigned hx = (unsigned)__half_as_ushort(__float2half(fx));
    unsigned hy = (unsigned)__half_as_ushort(__float2half(fy));
    unsigned hz = (unsigned)__half_as_ushort(__float2half(fz));
    uint2 r;
    r.x = hx | (hy << 16);
    r.y = hz | ((unsigned)local << 16);
    return r;
}

// Phase A: SINGLE-PASS per 8192-edge block. EPB 4096->8192 at 512 threads:
// LDS 75.4KB -> 2 blocks/CU (16 waves, ~50% occupancy, up from 36%) while
// HALVING per-block overheads (scan, global reservations) and doubling
// copy-out run lengths. Same records, same atomic lanes, same stream.
__global__ __launch_bounds__(BIN_T) void bin_kernel(
    const float* __restrict__ raw_charges,
    const float* __restrict__ A,
    const float* __restrict__ rho,
    const float* __restrict__ C,
    const float* __restrict__ distances,
    const float* __restrict__ uv,            // [E,3]
    const int*   __restrict__ edge_src,
    const int*   __restrict__ pair_indices,
    const int*   __restrict__ src_elem,
    const int*   __restrict__ tgt_elem,
    int*   __restrict__ g_cnt,               // [nb]
    uint2* __restrict__ buf,                 // [nb][cap]
    int cap, int n_edges, int nb)
{
    __shared__ float s_AoR[NUM_PAIRS], s_invRho[NUM_PAIRS], s_C6[NUM_PAIRS], s_qq[16];
    __shared__ int hcnt[MAX_BK], hexcl[MAX_BK], gbase[MAX_BK];
    __shared__ int s_wsum[2];
    __shared__ uint2 s_rec[EPB];             // 64 KB
    __shared__ unsigned char s_bb[EPB];      // 8 KB

    const int t = threadIdx.x;
    load_params(t, raw_charges, A, rho, C, s_AoR, s_invRho, s_C6, s_qq);
    for (int k = t; k < nb; k += BIN_T) hcnt[k] = 0;
    __syncthreads();

    const int blk_base = blockIdx.x * EPB;
    const bool full = (blk_base + EPB) <= n_edges;

    if (full) {
        uint2 rec[NCHUNK * 4];               // packed records (32 VGPR)
        int   rkb[NCHUNK * 4];               // rank (low 16) | bucket (high 16)

        // fused load + compute + count (no barrier inside): loads for chunk
        // c+1 are in flight while chunk c computes / claims ranks.
#pragma unroll
        for (int c = 0; c < NCHUNK; ++c) {
            const int e0 = blk_base + c * BCHUNK + t * 4;
            int4   src4 = *(const int4*)(edge_src + e0);
            float4 d4  = *(const float4*)(distances + e0);
            int4   p4  = *(const int4*)(pair_indices + e0);
            int4   se4 = *(const int4*)(src_elem + e0);
            int4   te4 = *(const int4*)(tgt_elem + e0);
            const float4* uvp = (const float4*)(uv + 3 * (size_t)e0);
            float4 u0 = uvp[0], u1 = uvp[1], u2 = uvp[2];

            float dd[4] = {d4.x, d4.y, d4.z, d4.w};
            int   pp[4] = {p4.x, p4.y, p4.z, p4.w};
            int   ss[4] = {se4.x, se4.y, se4.z, se4.w};
            int   tt[4] = {te4.x, te4.y, te4.z, te4.w};
            float ux[4] = {u0.x, u0.w, u1.z, u2.y};
            float uy[4] = {u0.y, u1.x, u1.w, u2.z};
            float uz[4] = {u0.z, u1.y, u2.x, u2.w};
            int   nd[4] = {src4.x, src4.y, src4.z, src4.w};

#pragma unroll
            for (int k = 0; k < 4; ++k) {
                float d = dd[k];
                float inv_d2 = 1.0f / (d * d);
                float tot = edge_force(d, inv_d2, pp[k], ss[k], tt[k],
                                       s_AoR, s_invRho, s_C6, s_qq);
                int j = c * 4 + k;
                int bb = nd[k] >> BK_SHIFT;
                rec[j] = pack_rec(-tot * ux[k], -tot * uy[k], -tot * uz[k],
                                  nd[k] & (BK_NODES - 1));
                rkb[j] = atomicAdd(&hcnt[bb], 1) | (bb << 16);
            }
        }
        __syncthreads();

        // 2-wave shfl exclusive scan (nb <= 128) + global reservation
        {
            const int w = t >> 6, lane = t & 63;
            int v = 0, sum = 0;
            if (t < 128) {
                v = (t < nb) ? hcnt[t] : 0;
                sum = v;
#pragma unroll
                for (int off = 1; off < 64; off <<= 1) {
                    int u = __shfl_up(sum, off, 64);
                    if (lane >= off) sum += u;
                }
                if (lane == 63) s_wsum[w] = sum;
            }
            __syncthreads();
            if (t < nb) {
                hexcl[t] = sum - v + (w ? s_wsum[0] : 0);
                gbase[t] = v ? atomicAdd(&g_cnt[t], v) : 0;
            }
            __syncthreads();
        }

        // scatter registers -> bucket-sorted LDS slots
#pragma unroll
        for (int j = 0; j < NCHUNK * 4; ++j) {
            int bb = rkb[j] >> 16;
            int idx = hexcl[bb] + (rkb[j] & 0xffff);
            s_rec[idx] = rec[j];
            s_bb[idx] = (unsigned char)bb;
        }
        __syncthreads();

        // copy out bucket-sorted -> coalesced runs in global
#pragma unroll
        for (int k = 0; k < EPB / BIN_T; ++k) {
            int i = t + k * BIN_T;
            int bb = s_bb[i];
            int off = gbase[bb] + (i - hexcl[bb]);
            if (off < cap) buf[(size_t)bb * cap + off] = s_rec[i];
        }
    } else {
        // tail block: per-edge direct append
        for (int j = 0; j < EPB / BIN_T; ++j) {
            int e = blk_base + j * BIN_T + t;
            if (e >= n_edges) continue;
            float d = distances[e];
            float inv_d2 = 1.0f / (d * d);
            float total = edge_force(d, inv_d2, pair_indices[e],
                                     src_elem[e], tgt_elem[e],
                                     s_AoR, s_invRho, s_C6, s_qq);
            float vx = uv[3 * (size_t)e + 0];
            float vy = uv[3 * (size_t)e + 1];
            float vz = uv[3 * (size_t)e + 2];
            int node = edge_src[e];
            int bb = node >> BK_SHIFT;
            int pos = atomicAdd(&g_cnt[bb], 1);
            if (pos < cap)
                buf[(size_t)bb * cap + pos] =
                    pack_rec(-total * vx, -total * vy, -total * vz,
                             node & (BK_NODES - 1));
        }
    }
}

// Phase B: grid (S, nb); block (s,b) takes its slice of bucket b, counting-sorts
// the records by node in LDS (1 rtn-atomic lane/record), then each thread sums
// 4 nodes' runs in fp32 registers and writes a coalesced partial. (R4-proven,
// byte-identical.)
template<int SLOTS>
__global__ __launch_bounds__(256) void gather_kernel(
    const uint2* __restrict__ buf,
    const int*   __restrict__ g_cnt,
    float* __restrict__ part,        // [nb*S][BK_NODES*3]
    int cap)
{
    constexpr int KM = SLOTS / 256;
    __shared__ int   s_excl[BK_NODES];     // 4 KB: counts, then exclusive scan
    __shared__ int   s_wsum[4];
    __shared__ uint2 s_srt[SLOTS];         // node-sorted records

    const int s = blockIdx.x, S = gridDim.x, b = blockIdx.y;
    const int t = threadIdx.x;

    for (int k = t; k < BK_NODES; k += 256) s_excl[k] = 0;
    __syncthreads();

    int cnt = g_cnt[b];
    if (cnt > cap) cnt = cap;
    int lo = (int)((long)cnt * s / S);
    int hi = (int)((long)cnt * (s + 1) / S);

    const uint2* p = buf + (size_t)b * cap;

    // load slice into registers (all loads in flight), claim per-node ranks
    uint2 rec[KM];
    int   rk[KM];
#pragma unroll
    for (int k = 0; k < KM; ++k) {
        int i = lo + t + k * 256;
        if (i < hi) rec[k] = p[i];
    }
#pragma unroll
    for (int k = 0; k < KM; ++k) {
        int i = lo + t + k * 256;
        if (i < hi) rk[k] = atomicAdd(&s_excl[rec[k].y >> 16], 1);
    }
    __syncthreads();

    // exclusive scan of 1024 per-node counts, in place; counts kept in regs
    int c0, c1, c2, c3;
    {
        int n0 = t << 2;
        c0 = s_excl[n0]; c1 = s_excl[n0 + 1]; c2 = s_excl[n0 + 2]; c3 = s_excl[n0 + 3];
        int tsum = c0 + c1 + c2 + c3;
        int lane = t & 63, w = t >> 6;
        int run = tsum;
#pragma unroll
        for (int off = 1; off < 64; off <<= 1) {
            int u = __shfl_up(run, off, 64);
            if (lane >= off) run += u;
        }
        if (lane == 63) s_wsum[w] = run;
        __syncthreads();
        int wbase = 0;
        if (w > 0) wbase += s_wsum[0];
        if (w > 1) wbase += s_wsum[1];
        if (w > 2) wbase += s_wsum[2];
        int base = wbase + run - tsum;          // exclusive prefix for node n0
        s_excl[n0]     = base;
        s_excl[n0 + 1] = base + c0;
        s_excl[n0 + 2] = base + c0 + c1;
        s_excl[n0 + 3] = base + c0 + c1 + c2;
    }
    __syncthreads();

    // scatter records to node-sorted LDS slots (plain ds_write, no atomics)
#pragma unroll
    for (int k = 0; k < KM; ++k) {
        int i = lo + t + k * 256;
        if (i < hi) {
            int node = rec[k].y >> 16;
            s_srt[s_excl[node] + rk[k]] = rec[k];
        }
    }
    __syncthreads();

    // per-node register reduction (fp32), coalesced float4 write-out
    float out[12];
    int cq[4] = {c0, c1, c2, c3};
    int n0 = t << 2;
#pragma unroll
    for (int q = 0; q < 4; ++q) {
        int beg = s_excl[n0 + q], end = beg + cq[q];
        float fx = 0.f, fy = 0.f, fz = 0.f;
        for (int j = beg; j < end; ++j) {
            uint2 r = s_srt[j];
            fx += __half2float(__ushort_as_half((unsigned short)(r.x & 0xffff)));
            fy += __half2float(__ushort_as_half((unsigned short)(r.x >> 16)));
            fz += __half2float(__ushort_as_half((unsigned short)(r.y & 0xffff)));
        }
        out[q * 3 + 0] = fx; out[q * 3 + 1] = fy; out[q * 3 + 2] = fz;
    }
    float* op = part + ((size_t)b * S + s) * (BK_NODES * 3);
    float4* o4 = (float4*)op + t * 3;
    o4[0] = make_float4(out[0], out[1], out[2],  out[3]);
    o4[1] = make_float4(out[4], out[5], out[6],  out[7]);
    o4[2] = make_float4(out[8], out[9], out[10], out[11]);
}

// part layout: [nb][S][3072] floats; out float i -> bucket i/3072, offset i%3072.
// One thread per output float (latency-bound straggler needs concurrency).
__global__ __launch_bounds__(256) void reduce_kernel(
    const float* __restrict__ part, float* __restrict__ out, int n, int S)
{
    int i = blockIdx.x * blockDim.x + threadIdx.x;
    if (i >= n) return;
    int b = i / (BK_NODES * 3);
    int k = i - b * (BK_NODES * 3);
    const float* p = part + (size_t)b * S * (BK_NODES * 3) + k;
    float s = 0.f;
#pragma unroll 4
    for (int j = 0; j < S; ++j) s += p[(size_t)j * (BK_NODES * 3)];
    out[i] = s;
}

// Fallback: direct scatter with native fp32 atomics.
__global__ __launch_bounds__(256) void force_kernel_direct(
    const float* __restrict__ raw_charges,
    const float* __restrict__ A,
    const float* __restrict__ rho,
    const float* __restrict__ C,
    const float* __restrict__ distances,
    const float* __restrict__ uv,
    const int*   __restrict__ edge_src,
    const int*   __restrict__ pair_indices,
    const int*   __restrict__ src_elem,
    const int*   __restrict__ tgt_elem,
    float* __restrict__ forces,
    int n_edges)
{
    __shared__ float s_AoR[NUM_PAIRS], s_invRho[NUM_PAIRS], s_C6[NUM_PAIRS], s_qq[16];
    const int t = threadIdx.x;
    load_params(t, raw_charges, A, rho, C, s_AoR, s_invRho, s_C6, s_qq);
    __syncthreads();

    int e = blockIdx.x * blockDim.x + t;
    if (e >= n_edges) return;
    float d = distances[e];
    float inv_d2 = 1.0f / (d * d);
    float total = edge_force(d, inv_d2, pair_indices[e],
                             src_elem[e], tgt_elem[e], s_AoR, s_invRho, s_C6, s_qq);
    float ux = uv[3 * (size_t)e + 0], uy = uv[3 * (size_t)e + 1], uz = uv[3 * (size_t)e + 2];
    float* dst = forces + 3 * (size_t)edge_src[e];
    unsafeAtomicAdd(dst + 0, -total * ux);
    unsafeAtomicAdd(dst + 1, -total * uy);
    unsafeAtomicAdd(dst + 2, -total * uz);
}

extern "C" void kernel_launch(void* const* d_in, const int* in_sizes, int n_in,
                              void* d_out, int out_size, void* d_ws, size_t ws_size,
                              hipStream_t stream) {
    const float* raw_charges = (const float*)d_in[0];
    const float* A           = (const float*)d_in[1];
    const float* rho         = (const float*)d_in[2];
    const float* C           = (const float*)d_in[3];
    const float* distances   = (const float*)d_in[4];
    // d_in[5] (inverse_distances_sq) recomputed on the fly
    const float* uv          = (const float*)d_in[6];
    const int*   edge_index  = (const int*)d_in[7];   // [2, E]; row 0 = source
    const int*   pair_idx    = (const int*)d_in[8];
    const int*   src_elem    = (const int*)d_in[9];
    const int*   tgt_elem    = (const int*)d_in[10];

    float* forces = (float*)d_out;
    const int n_edges = in_sizes[4];
    const int n_out   = out_size;            // n_nodes * 3
    const int n_nodes = n_out / 3;

    const int B = 256;
    const int nb = (n_nodes + BK_NODES - 1) >> BK_SHIFT;

    long meanb = ((long)n_edges * BK_NODES) / (n_nodes > 0 ? n_nodes : 1);
    int cap = (int)(meanb + 8.0 * sqrt((double)(meanb > 0 ? meanb : 1)) + 256.0);
    cap = (cap + 255) & ~255;

    const size_t hdr = 8192;
    size_t off_buf = hdr;
    size_t sz_buf  = (size_t)nb * cap * sizeof(uint2);
    size_t off_part = (off_buf + sz_buf + 255) & ~(size_t)255;

    // pick S: prefer S=16 (R4-proven) if slice fits 4608 slots; else S=32
    int S = 0, slots = 0;
    {
        size_t need16 = off_part + (size_t)nb * 16 * (BK_NODES * 3) * sizeof(float);
        size_t need32 = off_part + (size_t)nb * 32 * (BK_NODES * 3) * sizeof(float);
        if (ws_size >= need16 && (cap + 15) / 16 <= 4608)       { S = 16; slots = 4608; }
        else if (ws_size >= need32 && (cap + 31) / 32 <= 2304)  { S = 32; slots = 2304; }
    }

    if (nb <= MAX_BK && S > 0 && (n_out % 4) == 0) {
        int*   g_cnt = (int*)d_ws;
        uint2* buf   = (uint2*)((char*)d_ws + off_buf);
        float* part  = (float*)((char*)d_ws + off_part);

        hipMemsetAsync(g_cnt, 0, nb * sizeof(int), stream);

        int gridA = (n_edges + EPB - 1) / EPB;
        bin_kernel<<<gridA, BIN_T, 0, stream>>>(raw_charges, A, rho, C,
                                                distances, uv,
                                                edge_index, pair_idx, src_elem, tgt_elem,
                                                g_cnt, buf, cap, n_edges, nb);

        dim3 gridB(S, nb);
        if (slots == 4608)
            gather_kernel<4608><<<gridB, B, 0, stream>>>(buf, g_cnt, part, cap);
        else
            gather_kernel<2304><<<gridB, B, 0, stream>>>(buf, g_cnt, part, cap);

        reduce_kernel<<<(n_out + B - 1) / B, B, 0, stream>>>(part, forces, n_out, S);
    } else {
        hipMemsetAsync(forces, 0, (size_t)n_out * sizeof(float), stream);
        int grid = (n_edges + B - 1) / B;
        force_kernel_direct<<<grid, B, 0, stream>>>(raw_charges, A, rho, C,
                                                    distances, uv,
                                                    edge_index, pair_idx,
                                                    src_elem, tgt_elem,
                                                    forces, n_edges);
    }
}

// Round 10
// 294.263 us; speedup vs baseline: 1.0328x; 1.0328x over previous
//
#include <hip/hip_runtime.h>
#include <hip/hip_fp16.h>
#include <math.h>

#define NUM_PAIRS 10
#define BK_SHIFT 10                // 1024 nodes per bucket
#define BK_NODES 1024
#define MAX_BK 128
#define EPB 4096                   // edges per bin block
#define BIN_T 512                  // bin block threads (8 waves -> latency hiding)
#define NCHUNK 2                   // 2 chunks of 4 edges/thread (8 edges/thread)
#define BCHUNK (BIN_T * 4)         // edges per chunk

__device__ __forceinline__ void load_params(
    int t,
    const float* __restrict__ raw_charges,
    const float* __restrict__ A,
    const float* __restrict__ rho,
    const float* __restrict__ C,
    float* s_AoR, float* s_invRho, float* s_C6, float* s_qq)
{
    if (t < NUM_PAIRS) {
        float r = rho[t];
        float ir = 1.0f / r;
        s_invRho[t] = ir;
        s_AoR[t]    = A[t] * ir;
        s_C6[t]     = 6.0f * C[t];
    }
    if (t < 16) {
        float q0 = raw_charges[0];
        // charges: [Cd, Se, S, Zn] = [q0, -q0, raw[1], raw[2]]
        float qs0 = q0, qs1 = -q0, qs2 = raw_charges[1], qs3 = raw_charges[2];
        float qa = (t & 3) == 0 ? qs0 : (t & 3) == 1 ? qs1 : (t & 3) == 2 ? qs2 : qs3;
        int hb = t >> 2;
        float qb = hb == 0 ? qs0 : hb == 1 ? qs1 : hb == 2 ? qs2 : qs3;
        s_qq[t] = qa * qb;
    }
}

__device__ __forceinline__ float edge_force(
    float d, float inv_d2, int p, int se, int te,
    const float* s_AoR, const float* s_invRho, const float* s_C6, const float* s_qq)
{
    float inv_d  = inv_d2 * d;                 // 1/d without a division
    float inv_d6 = inv_d2 * inv_d2 * inv_d2;
    float pot  = s_AoR[p] * __expf(-d * s_invRho[p]) - s_C6[p] * inv_d6 * inv_d;
    float coul = s_qq[(te << 2) | se] * inv_d2;
    return pot + coul;
}

// 8-byte record: fp16 fx,fy,fz + 10-bit bucket-local node index
__device__ __forceinline__ uint2 pack_rec(float fx, float fy, float fz, int local) {
    unsigned hx = (unsigned)__half_as_ushort(__float2half(fx));
    unsigned hy = (unsigned)__half_as_ushort(__float2half(fy));
    unsigned hz = (unsigned)__half_as_ushort(__float2half(fz));
    uint2 r;
    r.x = hx | (hy << 16);
    r.y = hz | ((unsigned)local << 16);
    return r;
}

// Phase A: SINGLE-PASS per 4096-edge block at 512 threads / 8 edges/thread
// (R8-proven optimum: 36% occupancy, 98us). Fused load+compute+rank-claim,
// then scan -> LDS bucket-sort -> coalesced copy-out.
__global__ __launch_bounds__(BIN_T) void bin_kernel(
    const float* __restrict__ raw_charges,
    const float* __restrict__ A,
    const float* __restrict__ rho,
    const float* __restrict__ C,
    const float* __restrict__ distances,
    const float* __restrict__ uv,            // [E,3]
    const int*   __restrict__ edge_src,
    const int*   __restrict__ pair_indices,
    const int*   __restrict__ src_elem,
    const int*   __restrict__ tgt_elem,
    int*   __restrict__ g_cnt,               // [nb]
    uint2* __restrict__ buf,                 // [nb][cap]
    int cap, int n_edges, int nb)
{
    __shared__ float s_AoR[NUM_PAIRS], s_invRho[NUM_PAIRS], s_C6[NUM_PAIRS], s_qq[16];
    __shared__ int hcnt[MAX_BK], hexcl[MAX_BK], gbase[MAX_BK];
    __shared__ int s_wsum[2];
    __shared__ uint2 s_rec[EPB];             // 32 KB
    __shared__ unsigned char s_bb[EPB];      // 4 KB

    const int t = threadIdx.x;
    load_params(t, raw_charges, A, rho, C, s_AoR, s_invRho, s_C6, s_qq);
    for (int k = t; k < nb; k += BIN_T) hcnt[k] = 0;
    __syncthreads();

    const int blk_base = blockIdx.x * EPB;
    const bool full = (blk_base + EPB) <= n_edges;

    if (full) {
        uint2 rec[NCHUNK * 4];               // packed records (16 VGPR)
        int   rkb[NCHUNK * 4];               // rank (low 16) | bucket (high 16)

        // fused load + compute + count (no barrier inside): loads for chunk
        // c+1 are in flight while chunk c computes / claims ranks.
#pragma unroll
        for (int c = 0; c < NCHUNK; ++c) {
            const int e0 = blk_base + c * BCHUNK + t * 4;
            int4   src4 = *(const int4*)(edge_src + e0);
            float4 d4  = *(const float4*)(distances + e0);
            int4   p4  = *(const int4*)(pair_indices + e0);
            int4   se4 = *(const int4*)(src_elem + e0);
            int4   te4 = *(const int4*)(tgt_elem + e0);
            const float4* uvp = (const float4*)(uv + 3 * (size_t)e0);
            float4 u0 = uvp[0], u1 = uvp[1], u2 = uvp[2];

            float dd[4] = {d4.x, d4.y, d4.z, d4.w};
            int   pp[4] = {p4.x, p4.y, p4.z, p4.w};
            int   ss[4] = {se4.x, se4.y, se4.z, se4.w};
            int   tt[4] = {te4.x, te4.y, te4.z, te4.w};
            float ux[4] = {u0.x, u0.w, u1.z, u2.y};
            float uy[4] = {u0.y, u1.x, u1.w, u2.z};
            float uz[4] = {u0.z, u1.y, u2.x, u2.w};
            int   nd[4] = {src4.x, src4.y, src4.z, src4.w};

#pragma unroll
            for (int k = 0; k < 4; ++k) {
                float d = dd[k];
                float inv_d2 = 1.0f / (d * d);
                float tot = edge_force(d, inv_d2, pp[k], ss[k], tt[k],
                                       s_AoR, s_invRho, s_C6, s_qq);
                int j = c * 4 + k;
                int bb = nd[k] >> BK_SHIFT;
                rec[j] = pack_rec(-tot * ux[k], -tot * uy[k], -tot * uz[k],
                                  nd[k] & (BK_NODES - 1));
                rkb[j] = atomicAdd(&hcnt[bb], 1) | (bb << 16);
            }
        }
        __syncthreads();

        // 2-wave shfl exclusive scan (nb <= 128) + global reservation
        {
            const int w = t >> 6, lane = t & 63;
            int v = 0, sum = 0;
            if (t < 128) {
                v = (t < nb) ? hcnt[t] : 0;
                sum = v;
#pragma unroll
                for (int off = 1; off < 64; off <<= 1) {
                    int u = __shfl_up(sum, off, 64);
                    if (lane >= off) sum += u;
                }
                if (lane == 63) s_wsum[w] = sum;
            }
            __syncthreads();
            if (t < nb) {
                hexcl[t] = sum - v + (w ? s_wsum[0] : 0);
                gbase[t] = v ? atomicAdd(&g_cnt[t], v) : 0;
            }
            __syncthreads();
        }

        // scatter registers -> bucket-sorted LDS slots
#pragma unroll
        for (int j = 0; j < NCHUNK * 4; ++j) {
            int bb = rkb[j] >> 16;
            int idx = hexcl[bb] + (rkb[j] & 0xffff);
            s_rec[idx] = rec[j];
            s_bb[idx] = (unsigned char)bb;
        }
        __syncthreads();

        // copy out bucket-sorted -> coalesced runs in global
#pragma unroll
        for (int k = 0; k < EPB / BIN_T; ++k) {
            int i = t + k * BIN_T;
            int bb = s_bb[i];
            int off = gbase[bb] + (i - hexcl[bb]);
            if (off < cap) buf[(size_t)bb * cap + off] = s_rec[i];
        }
    } else {
        // tail block: per-edge direct append
        for (int j = 0; j < EPB / BIN_T; ++j) {
            int e = blk_base + j * BIN_T + t;
            if (e >= n_edges) continue;
            float d = distances[e];
            float inv_d2 = 1.0f / (d * d);
            float total = edge_force(d, inv_d2, pair_indices[e],
                                     src_elem[e], tgt_elem[e],
                                     s_AoR, s_invRho, s_C6, s_qq);
            float vx = uv[3 * (size_t)e + 0];
            float vy = uv[3 * (size_t)e + 1];
            float vz = uv[3 * (size_t)e + 2];
            int node = edge_src[e];
            int bb = node >> BK_SHIFT;
            int pos = atomicAdd(&g_cnt[bb], 1);
            if (pos < cap)
                buf[(size_t)bb * cap + pos] =
                    pack_rec(-total * vx, -total * vy, -total * vz,
                             node & (BK_NODES - 1));
        }
    }
}

// Phase B: grid (S, nb); block (s,b) takes its slice of bucket b, counting-sorts
// the records by node in LDS (1 rtn-atomic lane/record), then each thread sums
// 4 nodes' runs in fp32 registers and writes a coalesced partial. (R4-proven.)
template<int SLOTS>
__global__ __launch_bounds__(256) void gather_kernel(
    const uint2* __restrict__ buf,
    const int*   __restrict__ g_cnt,
    float* __restrict__ part,        // [nb*S][BK_NODES*3]
    int cap)
{
    constexpr int KM = SLOTS / 256;
    __shared__ int   s_excl[BK_NODES];     // 4 KB: counts, then exclusive scan
    __shared__ int   s_wsum[4];
    __shared__ uint2 s_srt[SLOTS];         // node-sorted records

    const int s = blockIdx.x, S = gridDim.x, b = blockIdx.y;
    const int t = threadIdx.x;

    for (int k = t; k < BK_NODES; k += 256) s_excl[k] = 0;
    __syncthreads();

    int cnt = g_cnt[b];
    if (cnt > cap) cnt = cap;
    int lo = (int)((long)cnt * s / S);
    int hi = (int)((long)cnt * (s + 1) / S);

    const uint2* p = buf + (size_t)b * cap;

    // load slice into registers (all loads in flight), claim per-node ranks
    uint2 rec[KM];
    int   rk[KM];
#pragma unroll
    for (int k = 0; k < KM; ++k) {
        int i = lo + t + k * 256;
        if (i < hi) rec[k] = p[i];
    }
#pragma unroll
    for (int k = 0; k < KM; ++k) {
        int i = lo + t + k * 256;
        if (i < hi) rk[k] = atomicAdd(&s_excl[rec[k].y >> 16], 1);
    }
    __syncthreads();

    // exclusive scan of 1024 per-node counts, in place; counts kept in regs
    int c0, c1, c2, c3;
    {
        int n0 = t << 2;
        c0 = s_excl[n0]; c1 = s_excl[n0 + 1]; c2 = s_excl[n0 + 2]; c3 = s_excl[n0 + 3];
        int tsum = c0 + c1 + c2 + c3;
        int lane = t & 63, w = t >> 6;
        int run = tsum;
#pragma unroll
        for (int off = 1; off < 64; off <<= 1) {
            int u = __shfl_up(run, off, 64);
            if (lane >= off) run += u;
        }
        if (lane == 63) s_wsum[w] = run;
        __syncthreads();
        int wbase = 0;
        if (w > 0) wbase += s_wsum[0];
        if (w > 1) wbase += s_wsum[1];
        if (w > 2) wbase += s_wsum[2];
        int base = wbase + run - tsum;          // exclusive prefix for node n0
        s_excl[n0]     = base;
        s_excl[n0 + 1] = base + c0;
        s_excl[n0 + 2] = base + c0 + c1;
        s_excl[n0 + 3] = base + c0 + c1 + c2;
    }
    __syncthreads();

    // scatter records to node-sorted LDS slots (plain ds_write, no atomics)
#pragma unroll
    for (int k = 0; k < KM; ++k) {
        int i = lo + t + k * 256;
        if (i < hi) {
            int node = rec[k].y >> 16;
            s_srt[s_excl[node] + rk[k]] = rec[k];
        }
    }
    __syncthreads();

    // per-node register reduction (fp32), coalesced float4 write-out
    float out[12];
    int cq[4] = {c0, c1, c2, c3};
    int n0 = t << 2;
#pragma unroll
    for (int q = 0; q < 4; ++q) {
        int beg = s_excl[n0 + q], end = beg + cq[q];
        float fx = 0.f, fy = 0.f, fz = 0.f;
        for (int j = beg; j < end; ++j) {
            uint2 r = s_srt[j];
            fx += __half2float(__ushort_as_half((unsigned short)(r.x & 0xffff)));
            fy += __half2float(__ushort_as_half((unsigned short)(r.x >> 16)));
            fz += __half2float(__ushort_as_half((unsigned short)(r.y & 0xffff)));
        }
        out[q * 3 + 0] = fx; out[q * 3 + 1] = fy; out[q * 3 + 2] = fz;
    }
    float* op = part + ((size_t)b * S + s) * (BK_NODES * 3);
    float4* o4 = (float4*)op + t * 3;
    o4[0] = make_float4(out[0], out[1], out[2],  out[3]);
    o4[1] = make_float4(out[4], out[5], out[6],  out[7]);
    o4[2] = make_float4(out[8], out[9], out[10], out[11]);
}

// part layout: [nb][S][3072] floats; out float i -> bucket i/3072, offset i%3072.
// One thread per output float (latency-bound straggler needs concurrency).
__global__ __launch_bounds__(256) void reduce_kernel(
    const float* __restrict__ part, float* __restrict__ out, int n, int S)
{
    int i = blockIdx.x * blockDim.x + threadIdx.x;
    if (i >= n) return;
    int b = i / (BK_NODES * 3);
    int k = i - b * (BK_NODES * 3);
    const float* p = part + (size_t)b * S * (BK_NODES * 3) + k;
    float s = 0.f;
#pragma unroll 4
    for (int j = 0; j < S; ++j) s += p[(size_t)j * (BK_NODES * 3)];
    out[i] = s;
}

// Fallback: direct scatter with native fp32 atomics.
__global__ __launch_bounds__(256) void force_kernel_direct(
    const float* __restrict__ raw_charges,
    const float* __restrict__ A,
    const float* __restrict__ rho,
    const float* __restrict__ C,
    const float* __restrict__ distances,
    const float* __restrict__ uv,
    const int*   __restrict__ edge_src,
    const int*   __restrict__ pair_indices,
    const int*   __restrict__ src_elem,
    const int*   __restrict__ tgt_elem,
    float* __restrict__ forces,
    int n_edges)
{
    __shared__ float s_AoR[NUM_PAIRS], s_invRho[NUM_PAIRS], s_C6[NUM_PAIRS], s_qq[16];
    const int t = threadIdx.x;
    load_params(t, raw_charges, A, rho, C, s_AoR, s_invRho, s_C6, s_qq);
    __syncthreads();

    int e = blockIdx.x * blockDim.x + t;
    if (e >= n_edges) return;
    float d = distances[e];
    float inv_d2 = 1.0f / (d * d);
    float total = edge_force(d, inv_d2, pair_indices[e],
                             src_elem[e], tgt_elem[e], s_AoR, s_invRho, s_C6, s_qq);
    float ux = uv[3 * (size_t)e + 0], uy = uv[3 * (size_t)e + 1], uz = uv[3 * (size_t)e + 2];
    float* dst = forces + 3 * (size_t)edge_src[e];
    unsafeAtomicAdd(dst + 0, -total * ux);
    unsafeAtomicAdd(dst + 1, -total * uy);
    unsafeAtomicAdd(dst + 2, -total * uz);
}

extern "C" void kernel_launch(void* const* d_in, const int* in_sizes, int n_in,
                              void* d_out, int out_size, void* d_ws, size_t ws_size,
                              hipStream_t stream) {
    const float* raw_charges = (const float*)d_in[0];
    const float* A           = (const float*)d_in[1];
    const float* rho         = (const float*)d_in[2];
    const float* C           = (const float*)d_in[3];
    const float* distances   = (const float*)d_in[4];
    // d_in[5] (inverse_distances_sq) recomputed on the fly
    const float* uv          = (const float*)d_in[6];
    const int*   edge_index  = (const int*)d_in[7];   // [2, E]; row 0 = source
    const int*   pair_idx    = (const int*)d_in[8];
    const int*   src_elem    = (const int*)d_in[9];
    const int*   tgt_elem    = (const int*)d_in[10];

    float* forces = (float*)d_out;
    const int n_edges = in_sizes[4];
    const int n_out   = out_size;            // n_nodes * 3
    const int n_nodes = n_out / 3;

    const int B = 256;
    const int nb = (n_nodes + BK_NODES - 1) >> BK_SHIFT;

    long meanb = ((long)n_edges * BK_NODES) / (n_nodes > 0 ? n_nodes : 1);
    int cap = (int)(meanb + 8.0 * sqrt((double)(meanb > 0 ? meanb : 1)) + 256.0);
    cap = (cap + 255) & ~255;

    const size_t hdr = 8192;
    size_t off_buf = hdr;
    size_t sz_buf  = (size_t)nb * cap * sizeof(uint2);
    size_t off_part = (off_buf + sz_buf + 255) & ~(size_t)255;

    // pick S: prefer S=16 (R4-proven) if slice fits 4608 slots; else S=32
    int S = 0, slots = 0;
    {
        size_t need16 = off_part + (size_t)nb * 16 * (BK_NODES * 3) * sizeof(float);
        size_t need32 = off_part + (size_t)nb * 32 * (BK_NODES * 3) * sizeof(float);
        if (ws_size >= need16 && (cap + 15) / 16 <= 4608)       { S = 16; slots = 4608; }
        else if (ws_size >= need32 && (cap + 31) / 32 <= 2304)  { S = 32; slots = 2304; }
    }

    if (nb <= MAX_BK && S > 0 && (n_out % 4) == 0) {
        int*   g_cnt = (int*)d_ws;
        uint2* buf   = (uint2*)((char*)d_ws + off_buf);
        float* part  = (float*)((char*)d_ws + off_part);

        hipMemsetAsync(g_cnt, 0, nb * sizeof(int), stream);

        int gridA = (n_edges + EPB - 1) / EPB;
        bin_kernel<<<gridA, BIN_T, 0, stream>>>(raw_charges, A, rho, C,
                                                distances, uv,
                                                edge_index, pair_idx, src_elem, tgt_elem,
                                                g_cnt, buf, cap, n_edges, nb);

        dim3 gridB(S, nb);
        if (slots == 4608)
            gather_kernel<4608><<<gridB, B, 0, stream>>>(buf, g_cnt, part, cap);
        else
            gather_kernel<2304><<<gridB, B, 0, stream>>>(buf, g_cnt, part, cap);

        reduce_kernel<<<(n_out + B - 1) / B, B, 0, stream>>>(part, forces, n_out, S);
    } else {
        hipMemsetAsync(forces, 0, (size_t)n_out * sizeof(float), stream);
        int grid = (n_edges + B - 1) / B;
        force_kernel_direct<<<grid, B, 0, stream>>>(raw_charges, A, rho, C,
                                                    distances, uv,
                                                    edge_index, pair_idx,
                                                    src_elem, tgt_elem,
                                                    forces, n_edges);
    }
}